// Round 2
// baseline (2895.166 us; speedup 1.0000x reference)
//
#include <hip/hip_runtime.h>
#include <hip/hip_bf16.h>
#include <math.h>

#define SEQ 3072
#define DIM 1536
#define NH 12
#define HD 128
#define NB 24
#define BLKT 128
#define NBSQ 576          // NB*NB
#define TOPK_N 128
#define EPSV 1e-5f
#define SCALEV 0.08838834764831845f   // 1/sqrt(128)

__device__ __forceinline__ float b2f(unsigned short u) {
  return __uint_as_float(((unsigned int)u) << 16);
}
__device__ __forceinline__ float cvt(__hip_bfloat16 x) { return __bfloat162float(x); }

// Read input element i as fp32, dtype selected by runtime flag (uniform).
__device__ __forceinline__ float ldin(const void* p, size_t i, int f32) {
  return f32 ? ((const float*)p)[i]
             : __bfloat162float(((const __hip_bfloat16*)p)[i]);
}

// ---------------------------------------------------------------------------
// Detect whether inputs are bf16 or fp32: read weight buffer as bf16; fp32
// memory reinterpreted as bf16 has ~45% |v|>1e3 (random exponent low halves).
// flag[0] = 1 if fp32 inputs, else 0.  flag[1] = constant 0.
// ---------------------------------------------------------------------------
__global__ __launch_bounds__(256)
void dtype_probe(const void* __restrict__ w, int* __restrict__ flag) {
  __shared__ int cnt;
  if (threadIdx.x == 0) cnt = 0;
  __syncthreads();
  const __hip_bfloat16* p = (const __hip_bfloat16*)w;
  int local = 0;
  for (int i = threadIdx.x; i < 4096; i += 256) {
    float v = cvt(p[i]);
    if (!(fabsf(v) <= 1e3f)) local++;   // counts huge and NaN
  }
  atomicAdd(&cnt, local);
  __syncthreads();
  if (threadIdx.x == 0) { flag[0] = (cnt > 16) ? 1 : 0; flag[1] = 0; }
}

// ---------------------------------------------------------------------------
// C = A @ W^T + bias. A:[M,K], W:[N,K], bias:[N]. Dtypes by flags.
// 64x64 tile, BK=16, 256 threads, 4x4 per thread, fp32 accumulate.
// ---------------------------------------------------------------------------
__global__ __launch_bounds__(256)
void gemm_nt(const void* __restrict__ A, const void* __restrict__ W,
             const void* __restrict__ Bb, void* __restrict__ C,
             const int* __restrict__ af, const int* __restrict__ wf,
             const int* __restrict__ of, int M, int N, int K) {
  const int fA = *af, fW = *wf, fO = *of;
  __shared__ float As[16][68];
  __shared__ float Bs[16][68];
  const int tid = threadIdx.x;
  const int tx = tid & 15, ty = tid >> 4;
  const int col0 = blockIdx.x * 64;
  const int row0 = blockIdx.y * 64;

  float acc[4][4] = {};

  for (int k0 = 0; k0 < K; k0 += 16) {
#pragma unroll
    for (int i = 0; i < 4; i++) {
      int idx = i * 256 + tid;
      int c = idx & 15, r = idx >> 4;
      As[c][r] = ldin(A, (size_t)(row0 + r) * K + k0 + c, fA);
      Bs[c][r] = ldin(W, (size_t)(col0 + r) * K + k0 + c, fW);
    }
    __syncthreads();
#pragma unroll
    for (int kk = 0; kk < 16; kk++) {
      float a0 = As[kk][ty * 4 + 0], a1 = As[kk][ty * 4 + 1];
      float a2 = As[kk][ty * 4 + 2], a3 = As[kk][ty * 4 + 3];
      float b0 = Bs[kk][tx * 4 + 0], b1 = Bs[kk][tx * 4 + 1];
      float b2 = Bs[kk][tx * 4 + 2], b3 = Bs[kk][tx * 4 + 3];
      acc[0][0] += a0 * b0; acc[0][1] += a0 * b1; acc[0][2] += a0 * b2; acc[0][3] += a0 * b3;
      acc[1][0] += a1 * b0; acc[1][1] += a1 * b1; acc[1][2] += a1 * b2; acc[1][3] += a1 * b3;
      acc[2][0] += a2 * b0; acc[2][1] += a2 * b1; acc[2][2] += a2 * b2; acc[2][3] += a2 * b3;
      acc[3][0] += a3 * b0; acc[3][1] += a3 * b1; acc[3][2] += a3 * b2; acc[3][3] += a3 * b3;
    }
    __syncthreads();
  }

#pragma unroll
  for (int i = 0; i < 4; i++) {
    int row = row0 + ty * 4 + i;
#pragma unroll
    for (int j = 0; j < 4; j++) {
      int col = col0 + tx * 4 + j;
      float v = acc[i][j] + ldin(Bb, col, fW);
      size_t oi = (size_t)row * N + col;
      if (fO) ((float*)C)[oi] = v;
      else    ((__hip_bfloat16*)C)[oi] = __float2bfloat16(v);
    }
  }
}

// ---------------------------------------------------------------------------
// In-place RMSNorm + RoPE on one token row (bf16 storage, fp32 math).
// grid = SEQ, block = 256.
// ---------------------------------------------------------------------------
__global__ __launch_bounds__(256)
void rmsnorm_rope_kernel(__hip_bfloat16* __restrict__ x, const void* __restrict__ g,
                         const void* __restrict__ cs, const void* __restrict__ sn,
                         const int* __restrict__ f) {
  const int fI = *f;
  const int s = blockIdx.x, tid = threadIdx.x;
  __hip_bfloat16* row = x + (size_t)s * DIM;

  float ss = 0.f;
#pragma unroll
  for (int i = 0; i < 6; i++) {
    float v = cvt(row[tid + 256 * i]);
    ss += v * v;
  }
#pragma unroll
  for (int m = 32; m; m >>= 1) ss += __shfl_xor(ss, m, 64);
  __shared__ float wsum[4];
  if ((tid & 63) == 0) wsum[tid >> 6] = ss;
  __syncthreads();
  float tot = wsum[0] + wsum[1] + wsum[2] + wsum[3];
  float rn = rsqrtf(tot * (1.0f / DIM) + EPSV);

#pragma unroll
  for (int i = 0; i < 3; i++) {
    int p = tid + 256 * i;          // global pair index 0..767
    int pi = p & 63;                // within-head pair index
    float c  = ldin(cs, (size_t)s * 64 + pi, fI);
    float si = ldin(sn, (size_t)s * 64 + pi, fI);
    int d0 = 2 * p, d1 = 2 * p + 1;
    float xr = cvt(row[d0]) * rn * ldin(g, d0, fI);
    float xi = cvt(row[d1]) * rn * ldin(g, d1, fI);
    row[d0] = __float2bfloat16(xr * c - xi * si);
    row[d1] = __float2bfloat16(xr * si + xi * c);
  }
}

// ---------------------------------------------------------------------------
// Block-mean pooling (fp32 accumulate, deterministic). grid = (NB, DIM/256).
// ---------------------------------------------------------------------------
__global__ __launch_bounds__(256)
void pool_kernel(const __hip_bfloat16* __restrict__ x, float* __restrict__ out) {
  const int nb = blockIdx.x;
  const int d = blockIdx.y * 256 + threadIdx.x;
  float s = 0.f;
  for (int t = 0; t < BLKT; t++) s += cvt(x[(size_t)(nb * BLKT + t) * DIM + d]);
  out[nb * DIM + d] = s * (1.0f / BLKT);
}

// ---------------------------------------------------------------------------
// Draft block mask: pooled QK softmax + per-head top-128 threshold.
// grid = NH, block = 256.
// ---------------------------------------------------------------------------
__global__ __launch_bounds__(256)
void draft_mask_kernel(const float* __restrict__ qw, const float* __restrict__ kw,
                       int* __restrict__ bm) {
  const int h = blockIdx.x, tid = threadIdx.x;
  __shared__ float qh[NB][HD];
  __shared__ float kh[NB][HD];
  __shared__ float attn[NBSQ];
  __shared__ float cp[NBSQ];
  __shared__ float rv[4];
  __shared__ int ri[4];
  __shared__ float thr_sh;

  for (int idx = tid; idx < NB * HD; idx += 256) {
    int l = idx >> 7, d = idx & 127;
    qh[l][d] = qw[l * DIM + h * HD + d];
    kh[l][d] = kw[l * DIM + h * HD + d];
  }
  __syncthreads();

  for (int idx = tid; idx < NBSQ; idx += 256) {
    int l = idx / NB, m = idx % NB;
    int rl = l >> 2, cl = l & 3, rm = m >> 2, cm = m & 3;
    bool loc = (rm >= rl - 3) && (rm <= rl + 2) && (cm >= cl - 3) && (cm <= cl + 2);
    float sc;
    if (loc) {
      sc = 0.f;
      for (int d = 0; d < HD; d++) sc += qh[l][d] * kh[m][d];
      sc *= SCALEV;
    } else {
      sc = -INFINITY;
    }
    attn[idx] = sc;
  }
  __syncthreads();

  if (tid < NB) {
    float mx = -INFINITY;
    for (int m = 0; m < NB; m++) mx = fmaxf(mx, attn[tid * NB + m]);
    float sm = 0.f;
    for (int m = 0; m < NB; m++) {
      float p = expf(attn[tid * NB + m] - mx);
      attn[tid * NB + m] = p;
      sm += p;
    }
    float inv = 1.0f / sm;
    for (int m = 0; m < NB; m++) attn[tid * NB + m] *= inv;
  }
  __syncthreads();

  for (int idx = tid; idx < NBSQ; idx += 256) cp[idx] = attn[idx];
  __syncthreads();

  // 129 iterations of max-removal -> thr = 129th largest (exact top_k semantics)
  for (int it = 0; it <= TOPK_N; it++) {
    float bv = -INFINITY;
    int bi = -1;
    for (int idx = tid; idx < NBSQ; idx += 256) {
      if (cp[idx] > bv) { bv = cp[idx]; bi = idx; }
    }
#pragma unroll
    for (int m = 1; m < 64; m <<= 1) {
      float ov = __shfl_xor(bv, m, 64);
      int oi = __shfl_xor(bi, m, 64);
      if (ov > bv) { bv = ov; bi = oi; }
    }
    if ((tid & 63) == 0) { rv[tid >> 6] = bv; ri[tid >> 6] = bi; }
    __syncthreads();
    if (tid == 0) {
      float v = rv[0]; int b = ri[0];
      for (int w = 1; w < 4; w++) if (rv[w] > v) { v = rv[w]; b = ri[w]; }
      if (b >= 0) cp[b] = -INFINITY;
      thr_sh = v;
    }
    __syncthreads();
  }

  float thr = thr_sh;
  for (int idx = tid; idx < NBSQ; idx += 256)
    bm[h * NBSQ + idx] = (attn[idx] > thr) ? 1 : 0;
}

// ---------------------------------------------------------------------------
// Block-sparse flash attention. grid = (SEQ/16, NH), block = 256.
// bf16 q/k/v in, fp32 LDS tiles + math, bf16 out.
// ---------------------------------------------------------------------------
__global__ __launch_bounds__(256)
void attn_kernel(const __hip_bfloat16* __restrict__ q, const __hip_bfloat16* __restrict__ k,
                 const __hip_bfloat16* __restrict__ v, const int* __restrict__ bm,
                 __hip_bfloat16* __restrict__ o) {
  const int qt = blockIdx.x;          // 16-row q tile
  const int h = blockIdx.y;
  const int tid = threadIdx.x;
  const int s0 = qt * 16;
  const int qb = qt >> 3;             // 128-token q block index

  __shared__ float Qs[16][132];
  __shared__ float Ks[32][132];
  __shared__ float Vs[32][132];
  __shared__ float P[16][34];

#pragma unroll
  for (int i = 0; i < 2; i++) {       // 16*128/4 = 512 ushort4 chunks
    int ch = i * 256 + tid;
    int rr = ch >> 5, dc = (ch & 31) * 4;
    ushort4 u = *(const ushort4*)(q + (size_t)(s0 + rr) * DIM + h * HD + dc);
    Qs[rr][dc + 0] = b2f(u.x); Qs[rr][dc + 1] = b2f(u.y);
    Qs[rr][dc + 2] = b2f(u.z); Qs[rr][dc + 3] = b2f(u.w);
  }

  const int r = tid >> 4;
  const int c = tid & 15;
  float m_i = -INFINITY, l_i = 0.f;
  float oacc[8] = {0.f, 0.f, 0.f, 0.f, 0.f, 0.f, 0.f, 0.f};
  __syncthreads();

  for (int j = 0; j < NB; j++) {
    if (!bm[h * NBSQ + qb * NB + j]) continue;
    for (int sb = 0; sb < 4; sb++) {
      int t0 = j * BLKT + sb * 32;
#pragma unroll
      for (int i = 0; i < 4; i++) {   // 32*128/4 = 1024 ushort4 chunks
        int ch = i * 256 + tid;
        int t = ch >> 5, dc = (ch & 31) * 4;
        ushort4 ku = *(const ushort4*)(k + (size_t)(t0 + t) * DIM + h * HD + dc);
        ushort4 vu = *(const ushort4*)(v + (size_t)(t0 + t) * DIM + h * HD + dc);
        Ks[t][dc + 0] = b2f(ku.x); Ks[t][dc + 1] = b2f(ku.y);
        Ks[t][dc + 2] = b2f(ku.z); Ks[t][dc + 3] = b2f(ku.w);
        Vs[t][dc + 0] = b2f(vu.x); Vs[t][dc + 1] = b2f(vu.y);
        Vs[t][dc + 2] = b2f(vu.z); Vs[t][dc + 3] = b2f(vu.w);
      }
      __syncthreads();

      float sA = 0.f, sB = 0.f;
#pragma unroll
      for (int d = 0; d < HD; d += 4) {
        float4 qv = *(float4*)&Qs[r][d];
        float4 ka = *(float4*)&Ks[2 * c][d];
        float4 kb = *(float4*)&Ks[2 * c + 1][d];
        sA += qv.x * ka.x + qv.y * ka.y + qv.z * ka.z + qv.w * ka.w;
        sB += qv.x * kb.x + qv.y * kb.y + qv.z * kb.z + qv.w * kb.w;
      }
      sA *= SCALEV; sB *= SCALEV;

      float mloc = fmaxf(sA, sB);
#pragma unroll
      for (int mm = 1; mm < 16; mm <<= 1) mloc = fmaxf(mloc, __shfl_xor(mloc, mm, 64));
      float m_new = fmaxf(m_i, mloc);
      float alpha = expf(m_i - m_new);
      float pA = expf(sA - m_new), pB = expf(sB - m_new);
      float psum = pA + pB;
#pragma unroll
      for (int mm = 1; mm < 16; mm <<= 1) psum += __shfl_xor(psum, mm, 64);
      l_i = alpha * l_i + psum;
      m_i = m_new;
#pragma unroll
      for (int i = 0; i < 8; i++) oacc[i] *= alpha;
      P[r][2 * c] = pA;
      P[r][2 * c + 1] = pB;
      __syncthreads();

#pragma unroll
      for (int t = 0; t < 32; t++) {
        float p = P[r][t];
        float4 v0 = *(float4*)&Vs[t][c * 8];
        float4 v1 = *(float4*)&Vs[t][c * 8 + 4];
        oacc[0] += p * v0.x; oacc[1] += p * v0.y; oacc[2] += p * v0.z; oacc[3] += p * v0.w;
        oacc[4] += p * v1.x; oacc[5] += p * v1.y; oacc[6] += p * v1.z; oacc[7] += p * v1.w;
      }
      __syncthreads();
    }
  }

  float inv = (l_i > 0.f) ? 1.0f / l_i : 0.f;
#pragma unroll
  for (int i = 0; i < 8; i++)
    o[(size_t)(s0 + r) * DIM + h * HD + c * 8 + i] = __float2bfloat16(oacc[i] * inv);
}

// ---------------------------------------------------------------------------
extern "C" void kernel_launch(void* const* d_in, const int* in_sizes, int n_in,
                              void* d_out, int out_size, void* d_ws, size_t ws_size,
                              hipStream_t stream) {
  // workspace layout (36.3 MB total)
  char* wsb = (char*)d_ws;
  int*   flag = (int*)(wsb + 0);                         // [0]=fp32?, [1]=0
  float* qw   = (float*)(wsb + 64);                      // NB*DIM fp32
  float* kw   = (float*)(wsb + 64 + 147456);
  int*   bm   = (int*)(wsb + 64 + 2 * 147456);           // NH*NBSQ int
  __hip_bfloat16* q16 = (__hip_bfloat16*)(wsb + 322624);
  __hip_bfloat16* k16 = q16 + (size_t)SEQ * DIM;
  __hip_bfloat16* v16 = k16 + (size_t)SEQ * DIM;
  __hip_bfloat16* o16 = v16 + (size_t)SEQ * DIM;

  dtype_probe<<<1, 256, 0, stream>>>(d_in[1], flag);

  dim3 gg(DIM / 64, SEQ / 64);
  gemm_nt<<<gg, 256, 0, stream>>>(d_in[0], d_in[1], d_in[2], q16, flag, flag, flag + 1, SEQ, DIM, DIM);
  gemm_nt<<<gg, 256, 0, stream>>>(d_in[0], d_in[3], d_in[4], k16, flag, flag, flag + 1, SEQ, DIM, DIM);
  gemm_nt<<<gg, 256, 0, stream>>>(d_in[0], d_in[5], d_in[6], v16, flag, flag, flag + 1, SEQ, DIM, DIM);

  rmsnorm_rope_kernel<<<SEQ, 256, 0, stream>>>(q16, d_in[9],  d_in[11], d_in[12], flag);
  rmsnorm_rope_kernel<<<SEQ, 256, 0, stream>>>(k16, d_in[10], d_in[11], d_in[12], flag);

  pool_kernel<<<dim3(NB, DIM / 256), 256, 0, stream>>>(q16, qw);
  pool_kernel<<<dim3(NB, DIM / 256), 256, 0, stream>>>(k16, kw);

  draft_mask_kernel<<<NH, 256, 0, stream>>>(qw, kw, bm);

  attn_kernel<<<dim3(SEQ / 16, NH), 256, 0, stream>>>(q16, k16, v16, bm, o16);

  gemm_nt<<<gg, 256, 0, stream>>>(o16, d_in[7], d_in[8], d_out, flag + 1, flag, flag, SEQ, DIM, DIM);
}